// Round 1
// baseline (512.500 us; speedup 1.0000x reference)
//
#include <hip/hip_runtime.h>
#include <hip/hip_bf16.h>
#include <stdint.h>

typedef __attribute__((ext_vector_type(8))) short bf16x8;   // 8 bf16 = 4 VGPRs
typedef __attribute__((ext_vector_type(4))) float f32x4;

// ---------------- async global -> LDS (16B per lane) ----------------
__device__ __forceinline__ void gload_lds16(const void* g, void* l) {
  typedef __attribute__((address_space(1))) void gv_t;
  typedef __attribute__((address_space(3))) void lv_t;
  __builtin_amdgcn_global_load_lds((gv_t*)(uintptr_t)g,
                                   (lv_t*)(uint32_t)(uintptr_t)l, 16, 0, 0);
}

// ---------------- fp32 -> bf16 cast ----------------
__global__ __launch_bounds__(256) void cvt_bf16(const float* __restrict__ src,
                                                __hip_bfloat16* __restrict__ dst, int n4) {
  int i = blockIdx.x * 256 + threadIdx.x;
  if (i < n4) {
    float4 f = ((const float4*)src)[i];
    union { ushort4 u; __hip_bfloat16 h[4]; } pk;
    pk.h[0] = __float2bfloat16(f.x);
    pk.h[1] = __float2bfloat16(f.y);
    pk.h[2] = __float2bfloat16(f.z);
    pk.h[3] = __float2bfloat16(f.w);
    ((ushort4*)dst)[i] = pk.u;
  }
}

// ---------------- shared 128x128 bf16 GEMM body (A[M][K] @ B[N][K]^T) ----------------
// LDS: A tile [128][32] at 0 (8KB), B tile [128][32] at 8192. 16B-chunk XOR swizzle (row&3).
__device__ __forceinline__ void gemm_tile_compute(const __hip_bfloat16* __restrict__ A,
                                                  const __hip_bfloat16* __restrict__ Bm,
                                                  int K, int bm, int bn,
                                                  f32x4 acc[4][4], char* lbase) {
  const int tid = threadIdx.x;
  const int lane = tid & 63, w = tid >> 6;
  const int wr = w >> 1, wc = w & 1;
  const int rrow = lane & 15, g16 = lane >> 4;

  for (int k0 = 0; k0 < K; k0 += 32) {
    // stage A and B tiles: 8 chunks of 1KB each; wave w does chunks {w, w+4}
    #pragma unroll
    for (int i = 0; i < 2; ++i) {
      int c = i * 4 + w;
      int b = c * 1024 + (lane << 4);
      int row = b >> 6;           // 64B rows
      int cbs = ((b >> 4) & 3) ^ (row & 3);
      const char* ga = (const char*)(A + (size_t)(bm * 128 + row) * K + k0) + cbs * 16;
      gload_lds16(ga, lbase + c * 1024);
      const char* gb = (const char*)(Bm + (size_t)(bn * 128 + row) * K + k0) + cbs * 16;
      gload_lds16(gb, lbase + 8192 + c * 1024);
    }
    asm volatile("s_waitcnt vmcnt(0)" ::: "memory");
    __syncthreads();

    bf16x8 af[4], bfr[4];
    #pragma unroll
    for (int i = 0; i < 4; ++i) {
      int row = wr * 64 + i * 16 + rrow;
      af[i] = *(const bf16x8*)(lbase + row * 64 + ((g16 * 16) ^ ((row & 3) << 4)));
      int col = wc * 64 + i * 16 + rrow;
      bfr[i] = *(const bf16x8*)(lbase + 8192 + col * 64 + ((g16 * 16) ^ ((col & 3) << 4)));
    }
    #pragma unroll
    for (int i = 0; i < 4; ++i)
      #pragma unroll
      for (int j = 0; j < 4; ++j)
        acc[i][j] = __builtin_amdgcn_mfma_f32_16x16x32_bf16(af[i], bfr[j], acc[i][j], 0, 0, 0);
    __syncthreads();
  }
}

// ---------------- qkv GEMM: x(8192x768) @ qkv_w(2304x768)^T + b ----------------
__global__ __launch_bounds__(256) void gemm_qkv_kernel(
    const __hip_bfloat16* __restrict__ xb, const __hip_bfloat16* __restrict__ wqkv,
    const float* __restrict__ qkv_b,
    __hip_bfloat16* __restrict__ Qws, __hip_bfloat16* __restrict__ Kws,
    __hip_bfloat16* __restrict__ Vws, float* __restrict__ prekv) {
  __shared__ char smem[16384];
  f32x4 acc[4][4];
  const f32x4 z4 = {0.f, 0.f, 0.f, 0.f};
  #pragma unroll
  for (int i = 0; i < 4; ++i)
    #pragma unroll
    for (int j = 0; j < 4; ++j) acc[i][j] = z4;

  const int bn = blockIdx.x, bm = blockIdx.y;
  gemm_tile_compute(xb, wqkv, 768, bm, bn, acc, smem);

  const int lane = threadIdx.x & 63, w = threadIdx.x >> 6;
  const int wr = w >> 1, wc = w & 1;
  const int col0 = lane & 15, g = lane >> 4;
  #pragma unroll
  for (int j = 0; j < 4; ++j) {
    int n = bn * 128 + wc * 64 + j * 16 + col0;
    float bias = qkv_b[n];
    int which = n / 768;
    int head = (n >> 6) % 12;
    int d = n & 63;
    #pragma unroll
    for (int i = 0; i < 4; ++i) {
      #pragma unroll
      for (int r = 0; r < 4; ++r) {
        int m = bm * 128 + wr * 64 + i * 16 + g * 4 + r;
        float v = acc[i][j][r] + bias;
        int b = m >> 10, t = m & 1023;
        size_t idx = ((size_t)(b * 12 + head) << 16) + (t << 6) + d;
        __hip_bfloat16 hv = __float2bfloat16(v);
        if (which == 0) {
          Qws[idx] = hv;
        } else if (which == 1) {
          Kws[idx] = hv; prekv[idx] = v;
        } else {
          Vws[idx] = hv; prekv[6291456 + idx] = v;
        }
      }
    }
  }
}

// ---------------- proj GEMM: O(8192x768) @ proj_w(768x768)^T + b -> out ----------------
__global__ __launch_bounds__(256) void gemm_proj_kernel(
    const __hip_bfloat16* __restrict__ Ows, const __hip_bfloat16* __restrict__ wproj,
    const float* __restrict__ proj_b, float* __restrict__ out) {
  __shared__ char smem[16384];
  f32x4 acc[4][4];
  const f32x4 z4 = {0.f, 0.f, 0.f, 0.f};
  #pragma unroll
  for (int i = 0; i < 4; ++i)
    #pragma unroll
    for (int j = 0; j < 4; ++j) acc[i][j] = z4;

  const int bn = blockIdx.x, bm = blockIdx.y;
  gemm_tile_compute(Ows, wproj, 768, bm, bn, acc, smem);

  const int lane = threadIdx.x & 63, w = threadIdx.x >> 6;
  const int wr = w >> 1, wc = w & 1;
  const int col0 = lane & 15, g = lane >> 4;
  #pragma unroll
  for (int j = 0; j < 4; ++j) {
    int n = bn * 128 + wc * 64 + j * 16 + col0;
    float bias = proj_b[n];
    #pragma unroll
    for (int i = 0; i < 4; ++i) {
      #pragma unroll
      for (int r = 0; r < 4; ++r) {
        int m = bm * 128 + wr * 64 + i * 16 + g * 4 + r;
        out[(size_t)m * 768 + n] = acc[i][j][r] + bias;
      }
    }
  }
}

// ---------------- decomposed rel-pos projections: rel_h / rel_w ----------------
// relh[bh*1024+q][kh] = sum_c Q[bh,q,c] * rel_pos_h[(qh-kh+31)*64+c]; same for w with qw.
__global__ __launch_bounds__(256) void relbias_kernel(
    const __hip_bfloat16* __restrict__ Qws, const float* __restrict__ rph,
    const float* __restrict__ rpw, float* __restrict__ relh, float* __restrict__ relw) {
  const int tid = threadIdx.x, lane = tid & 63, wid = tid >> 6;
  int row_id = blockIdx.x * 4 + wid;           // [0, 98304)
  int q = row_id & 1023;
  int qh = q >> 5, qw = q & 31;
  float qv = __bfloat162float(Qws[(size_t)row_id * 64 + lane]);

  int sel = lane >> 5, kk = lane & 31;
  int idx = (sel == 0 ? qh : qw) - kk + 31;
  const float* trow = (sel == 0 ? rph : rpw) + idx * 64;

  float acc = 0.f;
  #pragma unroll
  for (int c4 = 0; c4 < 16; ++c4) {
    float4 t = ((const float4*)trow)[c4];
    acc += __shfl(qv, c4 * 4 + 0) * t.x;
    acc += __shfl(qv, c4 * 4 + 1) * t.y;
    acc += __shfl(qv, c4 * 4 + 2) * t.z;
    acc += __shfl(qv, c4 * 4 + 3) * t.w;
  }
  float* dst = (sel == 0 ? relh : relw);
  dst[(size_t)row_id * 32 + kk] = acc;
}

// ---------------- flash attention with decomposed rel bias ----------------
// grid: 96 bh * 8 q-tiles(128). 4 waves x 32 q-rows. K-tiles of 64.
__global__ __launch_bounds__(256) void flash_attn(
    const __hip_bfloat16* __restrict__ Qws, const __hip_bfloat16* __restrict__ Kws,
    const __hip_bfloat16* __restrict__ Vws, const float* __restrict__ relh,
    const float* __restrict__ relw, __hip_bfloat16* __restrict__ Ows) {
  __shared__ alignas(16) float s_relh[128 * 32];   // 16 KB
  __shared__ alignas(16) float s_relw[128 * 32];   // 16 KB
  __shared__ alignas(16) char s_kt[8192];          // K tile [64 key][64 hd] bf16, swizzled
  __shared__ alignas(16) char s_vt[8192];          // V^T    [64 hd][64 key] bf16, swizzled
  __shared__ alignas(16) char s_pt[16384];         // P per wave [32][64] bf16, swizzled

  const int tid = threadIdx.x, lane = tid & 63, w = tid >> 6;
  const int g16 = lane >> 4, c16 = lane & 15;
  const int bid = blockIdx.x;
  const int bh = bid >> 3, qt = bid & 7;
  const int q0 = qt * 128;
  const size_t bhbase = (size_t)bh << 16;          // bh*1024*64

  // stage rel tiles (contiguous 16KB each)
  {
    const float* gh = relh + ((size_t)bh << 15) + (q0 << 5);
    const float* gw = relw + ((size_t)bh << 15) + (q0 << 5);
    #pragma unroll
    for (int i = 0; i < 4; ++i) {
      int idx = (i * 256 + tid) * 4;
      *(float4*)&s_relh[idx] = *(const float4*)&gh[idx];
      *(float4*)&s_relw[idx] = *(const float4*)&gw[idx];
    }
  }

  // Q fragments (held in registers all along)
  bf16x8 qf[2][2];
  {
    const __hip_bfloat16* qp = Qws + bhbase + (size_t)(q0 + w * 32 + c16) * 64 + g16 * 8;
    qf[0][0] = *(const bf16x8*)qp;
    qf[0][1] = *(const bf16x8*)(qp + 32);
    qf[1][0] = *(const bf16x8*)(qp + 16 * 64);
    qf[1][1] = *(const bf16x8*)(qp + 16 * 64 + 32);
  }

  const f32x4 z4 = {0.f, 0.f, 0.f, 0.f};
  f32x4 o[2][4];
  float m_r[2][4], l_r[2][4];
  #pragma unroll
  for (int rb = 0; rb < 2; ++rb) {
    #pragma unroll
    for (int hf = 0; hf < 4; ++hf) o[rb][hf] = z4;
    #pragma unroll
    for (int r = 0; r < 4; ++r) { m_r[rb][r] = -1e30f; l_r[rb][r] = 0.f; }
  }

  __syncthreads();

  const float scale = 0.125f;
  for (int kt0 = 0; kt0 < 1024; kt0 += 64) {
    // --- stage K tile via global_load_lds (pre-swizzled source) ---
    #pragma unroll
    for (int i = 0; i < 2; ++i) {
      int c = w * 2 + i;
      int b = c * 1024 + (lane << 4);
      int row = b >> 7;                       // 128B rows (key)
      int cbs = ((b >> 4) & 7) ^ (row & 7);
      const char* g = (const char*)(Kws + bhbase + (size_t)(kt0 + row) * 64) + cbs * 16;
      gload_lds16(g, s_kt + c * 1024);
    }
    // --- stage V^T (reg scatter, swizzled) ---
    #pragma unroll
    for (int i = 0; i < 2; ++i) {
      int e = (i * 256 + tid) * 8;
      int key = e >> 6, hd0 = e & 63;
      bf16x8 vv = *(const bf16x8*)(Vws + bhbase + (size_t)(kt0 + key) * 64 + hd0);
      #pragma unroll
      for (int j = 0; j < 8; ++j) {
        int hd = hd0 + j;
        int byte = hd * 128 + ((key * 2) ^ ((hd & 7) << 4));
        *(short*)(s_vt + byte) = vv[j];
      }
    }
    asm volatile("s_waitcnt vmcnt(0)" ::: "memory");
    __syncthreads();

    // --- S = Q K^T ---
    f32x4 s[2][4];
    #pragma unroll
    for (int rb = 0; rb < 2; ++rb)
      #pragma unroll
      for (int kf = 0; kf < 4; ++kf) s[rb][kf] = z4;
    #pragma unroll
    for (int kc = 0; kc < 2; ++kc) {
      #pragma unroll
      for (int kf = 0; kf < 4; ++kf) {
        int key = kf * 16 + c16;
        int byte = key * 128 + (((kc * 32 + g16 * 8) * 2) ^ ((key & 7) << 4));
        bf16x8 kfr = *(const bf16x8*)(s_kt + byte);
        s[0][kf] = __builtin_amdgcn_mfma_f32_16x16x32_bf16(qf[0][kc], kfr, s[0][kf], 0, 0, 0);
        s[1][kf] = __builtin_amdgcn_mfma_f32_16x16x32_bf16(qf[1][kc], kfr, s[1][kf], 0, 0, 0);
      }
    }

    // --- scale + rel bias + online softmax + P->LDS ---
    #pragma unroll
    for (int rb = 0; rb < 2; ++rb) {
      #pragma unroll
      for (int kf = 0; kf < 4; ++kf) {
        int kh = (kt0 >> 5) + (kf >> 1);
        int kw = ((kf & 1) << 4) + c16;
        #pragma unroll
        for (int r = 0; r < 4; ++r) {
          int lrow = w * 32 + rb * 16 + g16 * 4 + r;
          s[rb][kf][r] = s[rb][kf][r] * scale + s_relh[lrow * 32 + kh] + s_relw[lrow * 32 + kw];
        }
      }
      #pragma unroll
      for (int r = 0; r < 4; ++r) {
        float tm = fmaxf(fmaxf(s[rb][0][r], s[rb][1][r]), fmaxf(s[rb][2][r], s[rb][3][r]));
        tm = fmaxf(tm, __shfl_xor(tm, 1));
        tm = fmaxf(tm, __shfl_xor(tm, 2));
        tm = fmaxf(tm, __shfl_xor(tm, 4));
        tm = fmaxf(tm, __shfl_xor(tm, 8));
        float mnew = fmaxf(m_r[rb][r], tm);
        float fac = __expf(m_r[rb][r] - mnew);
        m_r[rb][r] = mnew;
        float psum = 0.f;
        #pragma unroll
        for (int kf = 0; kf < 4; ++kf) {
          float p = __expf(s[rb][kf][r] - mnew);
          s[rb][kf][r] = p;
          psum += p;
        }
        psum += __shfl_xor(psum, 1);
        psum += __shfl_xor(psum, 2);
        psum += __shfl_xor(psum, 4);
        psum += __shfl_xor(psum, 8);
        l_r[rb][r] = l_r[rb][r] * fac + psum;
        #pragma unroll
        for (int hf = 0; hf < 4; ++hf) o[rb][hf] *= fac;
      }
      #pragma unroll
      for (int kf = 0; kf < 4; ++kf) {
        int key = kf * 16 + c16;
        #pragma unroll
        for (int r = 0; r < 4; ++r) {
          int prow = rb * 16 + g16 * 4 + r;
          int byte = w * 4096 + prow * 128 + ((key * 2) ^ ((prow & 7) << 4));
          *(__hip_bfloat16*)(s_pt + byte) = __float2bfloat16(s[rb][kf][r]);
        }
      }
    }
    __syncthreads();

    // --- O += P V ---
    #pragma unroll
    for (int kc = 0; kc < 2; ++kc) {
      bf16x8 pf[2];
      #pragma unroll
      for (int rb = 0; rb < 2; ++rb) {
        int prow = rb * 16 + c16;
        int byte = w * 4096 + prow * 128 + (((kc * 32 + g16 * 8) * 2) ^ ((prow & 7) << 4));
        pf[rb] = *(const bf16x8*)(s_pt + byte);
      }
      #pragma unroll
      for (int hf = 0; hf < 4; ++hf) {
        int hd = hf * 16 + c16;
        int byte = hd * 128 + (((kc * 32 + g16 * 8) * 2) ^ ((hd & 7) << 4));
        bf16x8 vf = *(const bf16x8*)(s_vt + byte);
        o[0][hf] = __builtin_amdgcn_mfma_f32_16x16x32_bf16(pf[0], vf, o[0][hf], 0, 0, 0);
        o[1][hf] = __builtin_amdgcn_mfma_f32_16x16x32_bf16(pf[1], vf, o[1][hf], 0, 0, 0);
      }
    }
    __syncthreads();
  }

  // --- epilogue: normalize + write O in (B,N,C) layout ---
  const int b = bh / 12, head = bh % 12;
  #pragma unroll
  for (int rb = 0; rb < 2; ++rb) {
    #pragma unroll
    for (int r = 0; r < 4; ++r) {
      int row = q0 + w * 32 + rb * 16 + g16 * 4 + r;
      float inv = 1.0f / l_r[rb][r];
      size_t base = ((size_t)b * 1024 + row) * 768 + head * 64;
      #pragma unroll
      for (int hf = 0; hf < 4; ++hf)
        Ows[base + hf * 16 + c16] = __float2bfloat16(o[rb][hf][r] * inv);
    }
  }
}

// ---------------- launch ----------------
extern "C" void kernel_launch(void* const* d_in, const int* in_sizes, int n_in,
                              void* d_out, int out_size, void* d_ws, size_t ws_size,
                              hipStream_t stream) {
  const float* x      = (const float*)d_in[0];
  const float* qkv_w  = (const float*)d_in[1];
  const float* qkv_b  = (const float*)d_in[2];
  const float* proj_w = (const float*)d_in[3];
  const float* proj_b = (const float*)d_in[4];
  const float* rph    = (const float*)d_in[5];
  const float* rpw    = (const float*)d_in[6];

  char* ws = (char*)d_ws;
  __hip_bfloat16* xb    = (__hip_bfloat16*)(ws);              // 12582912 B (reused as Ows)
  __hip_bfloat16* wqkv  = (__hip_bfloat16*)(ws + 12582912);   // 3538944 B
  __hip_bfloat16* wproj = (__hip_bfloat16*)(ws + 16121856);   // 1179648 B
  __hip_bfloat16* Qws   = (__hip_bfloat16*)(ws + 17301504);   // 12582912 B
  __hip_bfloat16* Kws   = (__hip_bfloat16*)(ws + 29884416);   // 12582912 B
  __hip_bfloat16* Vws   = (__hip_bfloat16*)(ws + 42467328);   // 12582912 B
  float* relh           = (float*)(ws + 55050240);            // 12582912 B
  float* relw           = (float*)(ws + 67633152);            // 12582912 B
  __hip_bfloat16* Ows   = xb;                                  // reuse (x consumed by qkv GEMM)

  float* out   = (float*)d_out;
  float* prekv = out + 6291456;

  cvt_bf16<<<6144, 256, 0, stream>>>(x, xb, 1572864);
  cvt_bf16<<<1728, 256, 0, stream>>>(qkv_w, wqkv, 442368);
  cvt_bf16<<<576, 256, 0, stream>>>(proj_w, wproj, 147456);
  gemm_qkv_kernel<<<dim3(18, 64), 256, 0, stream>>>(xb, wqkv, qkv_b, Qws, Kws, Vws, prekv);
  relbias_kernel<<<24576, 256, 0, stream>>>(Qws, rph, rpw, relh, relw);
  flash_attn<<<768, 256, 0, stream>>>(Qws, Kws, Vws, relh, relw, Ows);
  gemm_proj_kernel<<<dim3(6, 64), 256, 0, stream>>>(Ows, wproj, proj_b, out);
}

// Round 2
// 333.154 us; speedup vs baseline: 1.5383x; 1.5383x over previous
//
#include <hip/hip_runtime.h>
#include <hip/hip_bf16.h>
#include <stdint.h>

typedef __attribute__((ext_vector_type(8))) short bf16x8;   // 8 bf16 = 4 VGPRs
typedef __attribute__((ext_vector_type(4))) float f32x4;

// ---------------- async global -> LDS (16B per lane) ----------------
__device__ __forceinline__ void gload_lds16(const void* g, void* l) {
  typedef __attribute__((address_space(1))) void gv_t;
  typedef __attribute__((address_space(3))) void lv_t;
  __builtin_amdgcn_global_load_lds((gv_t*)(uintptr_t)g,
                                   (lv_t*)(uint32_t)(uintptr_t)l, 16, 0, 0);
}

// ---------------- fp32 -> bf16 cast ----------------
__global__ __launch_bounds__(256) void cvt_bf16(const float* __restrict__ src,
                                                __hip_bfloat16* __restrict__ dst, int n4) {
  int i = blockIdx.x * 256 + threadIdx.x;
  if (i < n4) {
    float4 f = ((const float4*)src)[i];
    union { ushort4 u; __hip_bfloat16 h[4]; } pk;
    pk.h[0] = __float2bfloat16(f.x);
    pk.h[1] = __float2bfloat16(f.y);
    pk.h[2] = __float2bfloat16(f.z);
    pk.h[3] = __float2bfloat16(f.w);
    ((ushort4*)dst)[i] = pk.u;
  }
}

// fp32 -> bf16 with zero-padding beyond n4src (for 63-row rel tables -> 64 rows)
__global__ __launch_bounds__(256) void cvt_bf16_pad(const float* __restrict__ src,
                                                    __hip_bfloat16* __restrict__ dst,
                                                    int n4src, int n4tot) {
  int i = blockIdx.x * 256 + threadIdx.x;
  if (i < n4tot) {
    float4 f = (i < n4src) ? ((const float4*)src)[i] : make_float4(0.f, 0.f, 0.f, 0.f);
    union { ushort4 u; __hip_bfloat16 h[4]; } pk;
    pk.h[0] = __float2bfloat16(f.x);
    pk.h[1] = __float2bfloat16(f.y);
    pk.h[2] = __float2bfloat16(f.z);
    pk.h[3] = __float2bfloat16(f.w);
    ((ushort4*)dst)[i] = pk.u;
  }
}

// ---------------- shared 128x128 bf16 GEMM body (A[M][K] @ B[N][K]^T) ----------------
// LDS: A tile [128][32] at 0 (8KB), B tile [128][32] at 8192. 16B-chunk XOR swizzle (row&3).
__device__ __forceinline__ void gemm_tile_compute(const __hip_bfloat16* __restrict__ A,
                                                  const __hip_bfloat16* __restrict__ Bm,
                                                  int K, int bm, int bn,
                                                  f32x4 acc[4][4], char* lbase) {
  const int tid = threadIdx.x;
  const int lane = tid & 63, w = tid >> 6;
  const int wr = w >> 1, wc = w & 1;
  const int rrow = lane & 15, g16 = lane >> 4;

  for (int k0 = 0; k0 < K; k0 += 32) {
    #pragma unroll
    for (int i = 0; i < 2; ++i) {
      int c = i * 4 + w;
      int b = c * 1024 + (lane << 4);
      int row = b >> 6;           // 64B rows
      int cbs = ((b >> 4) & 3) ^ (row & 3);
      const char* ga = (const char*)(A + (size_t)(bm * 128 + row) * K + k0) + cbs * 16;
      gload_lds16(ga, lbase + c * 1024);
      const char* gb = (const char*)(Bm + (size_t)(bn * 128 + row) * K + k0) + cbs * 16;
      gload_lds16(gb, lbase + 8192 + c * 1024);
    }
    asm volatile("s_waitcnt vmcnt(0)" ::: "memory");
    __syncthreads();

    bf16x8 af[4], bfr[4];
    #pragma unroll
    for (int i = 0; i < 4; ++i) {
      int row = wr * 64 + i * 16 + rrow;
      af[i] = *(const bf16x8*)(lbase + row * 64 + ((g16 * 16) ^ ((row & 3) << 4)));
      int col = wc * 64 + i * 16 + rrow;
      bfr[i] = *(const bf16x8*)(lbase + 8192 + col * 64 + ((g16 * 16) ^ ((col & 3) << 4)));
    }
    #pragma unroll
    for (int i = 0; i < 4; ++i)
      #pragma unroll
      for (int j = 0; j < 4; ++j)
        acc[i][j] = __builtin_amdgcn_mfma_f32_16x16x32_bf16(af[i], bfr[j], acc[i][j], 0, 0, 0);
    __syncthreads();
  }
}

// ---------------- qkv GEMM: x(8192x768) @ qkv_w(2304x768)^T + b ----------------
__global__ __launch_bounds__(256) void gemm_qkv_kernel(
    const __hip_bfloat16* __restrict__ xb, const __hip_bfloat16* __restrict__ wqkv,
    const float* __restrict__ qkv_b,
    __hip_bfloat16* __restrict__ Qws, __hip_bfloat16* __restrict__ Kws,
    __hip_bfloat16* __restrict__ Vws, float* __restrict__ prekv) {
  __shared__ char smem[16384];
  f32x4 acc[4][4];
  const f32x4 z4 = {0.f, 0.f, 0.f, 0.f};
  #pragma unroll
  for (int i = 0; i < 4; ++i)
    #pragma unroll
    for (int j = 0; j < 4; ++j) acc[i][j] = z4;

  const int bn = blockIdx.x, bm = blockIdx.y;
  gemm_tile_compute(xb, wqkv, 768, bm, bn, acc, smem);

  const int lane = threadIdx.x & 63, w = threadIdx.x >> 6;
  const int wr = w >> 1, wc = w & 1;
  const int col0 = lane & 15, g = lane >> 4;
  #pragma unroll
  for (int j = 0; j < 4; ++j) {
    int n = bn * 128 + wc * 64 + j * 16 + col0;
    float bias = qkv_b[n];
    int which = n / 768;
    int head = (n >> 6) % 12;
    int d = n & 63;
    #pragma unroll
    for (int i = 0; i < 4; ++i) {
      #pragma unroll
      for (int r = 0; r < 4; ++r) {
        int m = bm * 128 + wr * 64 + i * 16 + g * 4 + r;
        float v = acc[i][j][r] + bias;
        int b = m >> 10, t = m & 1023;
        size_t idx = ((size_t)(b * 12 + head) << 16) + (t << 6) + d;
        __hip_bfloat16 hv = __float2bfloat16(v);
        if (which == 0) {
          Qws[idx] = hv;
        } else if (which == 1) {
          Kws[idx] = hv; prekv[idx] = v;
        } else {
          Vws[idx] = hv; prekv[6291456 + idx] = v;
        }
      }
    }
  }
}

// ---------------- proj GEMM: O(8192x768) @ proj_w(768x768)^T + b -> out ----------------
__global__ __launch_bounds__(256) void gemm_proj_kernel(
    const __hip_bfloat16* __restrict__ Ows, const __hip_bfloat16* __restrict__ wproj,
    const float* __restrict__ proj_b, float* __restrict__ out) {
  __shared__ char smem[16384];
  f32x4 acc[4][4];
  const f32x4 z4 = {0.f, 0.f, 0.f, 0.f};
  #pragma unroll
  for (int i = 0; i < 4; ++i)
    #pragma unroll
    for (int j = 0; j < 4; ++j) acc[i][j] = z4;

  const int bn = blockIdx.x, bm = blockIdx.y;
  gemm_tile_compute(Ows, wproj, 768, bm, bn, acc, smem);

  const int lane = threadIdx.x & 63, w = threadIdx.x >> 6;
  const int wr = w >> 1, wc = w & 1;
  const int col0 = lane & 15, g = lane >> 4;
  #pragma unroll
  for (int j = 0; j < 4; ++j) {
    int n = bn * 128 + wc * 64 + j * 16 + col0;
    float bias = proj_b[n];
    #pragma unroll
    for (int i = 0; i < 4; ++i) {
      #pragma unroll
      for (int r = 0; r < 4; ++r) {
        int m = bm * 128 + wr * 64 + i * 16 + g * 4 + r;
        out[(size_t)m * 768 + n] = acc[i][j][r] + bias;
      }
    }
  }
}

// ---------------- flash attention with fused decomposed rel bias ----------------
// grid: 96 bh * 8 q-tiles(128). 4 waves x 32 q-rows. K-tiles of 64.
// Prologue computes Gh = Q @ rph^T, Gw = Q @ rpw^T (32x64 per wave via MFMA) and
// scatters the valid diagonal band into s_relh/s_relw (bias gather identity:
// rel_h[q,kh] = Gh[q, hq-kh+31], rel_w[q,kw] = Gw[q, wq-kw+31]).
__global__ __launch_bounds__(256) void flash_attn(
    const __hip_bfloat16* __restrict__ Qws, const __hip_bfloat16* __restrict__ Kws,
    const __hip_bfloat16* __restrict__ Vws, const __hip_bfloat16* __restrict__ rphb,
    const __hip_bfloat16* __restrict__ rpwb, __hip_bfloat16* __restrict__ Ows) {
  __shared__ alignas(16) float s_relh[128 * 32];   // 16 KB
  __shared__ alignas(16) float s_relw[128 * 32];   // 16 KB
  __shared__ alignas(16) char s_kt[8192];          // K tile [64 key][64 hd] bf16, swizzled
  __shared__ alignas(16) char s_vt[8192];          // V^T    [64 hd][64 key] bf16, swizzled
  __shared__ alignas(16) char s_pt[16384];         // P per wave [32][64] bf16, swizzled

  const int tid = threadIdx.x, lane = tid & 63, w = tid >> 6;
  const int g16 = lane >> 4, c16 = lane & 15;
  const int bid = blockIdx.x;
  const int bh = bid >> 3, qt = bid & 7;
  const int q0 = qt * 128;
  const size_t bhbase = (size_t)bh << 16;          // bh*1024*64

  // Q fragments (held in registers all along)
  bf16x8 qf[2][2];
  {
    const __hip_bfloat16* qp = Qws + bhbase + (size_t)(q0 + w * 32 + c16) * 64 + g16 * 8;
    qf[0][0] = *(const bf16x8*)qp;
    qf[0][1] = *(const bf16x8*)(qp + 32);
    qf[1][0] = *(const bf16x8*)(qp + 16 * 64);
    qf[1][1] = *(const bf16x8*)(qp + 16 * 64 + 32);
  }

  const f32x4 z4 = {0.f, 0.f, 0.f, 0.f};

  // --- rel-bias prologue: Gh/Gw = Q(32x64) @ table^T(64x64), then scatter ---
  {
    f32x4 gh[2][4], gw[2][4];
    #pragma unroll
    for (int mb = 0; mb < 2; ++mb)
      #pragma unroll
      for (int nf = 0; nf < 4; ++nf) { gh[mb][nf] = z4; gw[mb][nf] = z4; }
    #pragma unroll
    for (int kc = 0; kc < 2; ++kc) {
      #pragma unroll
      for (int nf = 0; nf < 4; ++nf) {
        int j = nf * 16 + c16;                 // table row (0..63; row 63 is zero pad)
        const __hip_bfloat16* tp = rphb + j * 64 + kc * 32 + g16 * 8;
        bf16x8 th = *(const bf16x8*)tp;
        bf16x8 tw = *(const bf16x8*)(rpwb + j * 64 + kc * 32 + g16 * 8);
        gh[0][nf] = __builtin_amdgcn_mfma_f32_16x16x32_bf16(qf[0][kc], th, gh[0][nf], 0, 0, 0);
        gh[1][nf] = __builtin_amdgcn_mfma_f32_16x16x32_bf16(qf[1][kc], th, gh[1][nf], 0, 0, 0);
        gw[0][nf] = __builtin_amdgcn_mfma_f32_16x16x32_bf16(qf[0][kc], tw, gw[0][nf], 0, 0, 0);
        gw[1][nf] = __builtin_amdgcn_mfma_f32_16x16x32_bf16(qf[1][kc], tw, gw[1][nf], 0, 0, 0);
      }
    }
    const int hq = (q0 >> 5) + w;              // h coordinate of this wave's 32 rows
    #pragma unroll
    for (int mb = 0; mb < 2; ++mb) {
      #pragma unroll
      for (int nf = 0; nf < 4; ++nf) {
        int j = nf * 16 + c16;
        int khh = hq - j + 31;
        #pragma unroll
        for (int r = 0; r < 4; ++r) {
          int rowin = mb * 16 + g16 * 4 + r;   // 0..31 within wave (== wq)
          int lrow = w * 32 + rowin;
          if (khh >= 0 && khh < 32) s_relh[lrow * 32 + khh] = gh[mb][nf][r];
          int kww = rowin - j + 31;
          if (kww >= 0 && kww < 32) s_relw[lrow * 32 + kww] = gw[mb][nf][r];
        }
      }
    }
  }

  f32x4 o[2][4];
  float m_r[2][4], l_r[2][4];
  #pragma unroll
  for (int rb = 0; rb < 2; ++rb) {
    #pragma unroll
    for (int hf = 0; hf < 4; ++hf) o[rb][hf] = z4;
    #pragma unroll
    for (int r = 0; r < 4; ++r) { m_r[rb][r] = -1e30f; l_r[rb][r] = 0.f; }
  }

  __syncthreads();

  const float scale = 0.125f;
  for (int kt0 = 0; kt0 < 1024; kt0 += 64) {
    // --- stage K tile via global_load_lds (pre-swizzled source) ---
    #pragma unroll
    for (int i = 0; i < 2; ++i) {
      int c = w * 2 + i;
      int b = c * 1024 + (lane << 4);
      int row = b >> 7;                       // 128B rows (key)
      int cbs = ((b >> 4) & 7) ^ (row & 7);
      const char* g = (const char*)(Kws + bhbase + (size_t)(kt0 + row) * 64) + cbs * 16;
      gload_lds16(g, s_kt + c * 1024);
    }
    // --- stage V^T (reg scatter, swizzled) ---
    #pragma unroll
    for (int i = 0; i < 2; ++i) {
      int e = (i * 256 + tid) * 8;
      int key = e >> 6, hd0 = e & 63;
      bf16x8 vv = *(const bf16x8*)(Vws + bhbase + (size_t)(kt0 + key) * 64 + hd0);
      #pragma unroll
      for (int j = 0; j < 8; ++j) {
        int hd = hd0 + j;
        int byte = hd * 128 + ((key * 2) ^ ((hd & 7) << 4));
        *(short*)(s_vt + byte) = vv[j];
      }
    }
    asm volatile("s_waitcnt vmcnt(0)" ::: "memory");
    __syncthreads();

    // --- S = Q K^T ---
    f32x4 s[2][4];
    #pragma unroll
    for (int rb = 0; rb < 2; ++rb)
      #pragma unroll
      for (int kf = 0; kf < 4; ++kf) s[rb][kf] = z4;
    #pragma unroll
    for (int kc = 0; kc < 2; ++kc) {
      #pragma unroll
      for (int kf = 0; kf < 4; ++kf) {
        int key = kf * 16 + c16;
        int byte = key * 128 + (((kc * 32 + g16 * 8) * 2) ^ ((key & 7) << 4));
        bf16x8 kfr = *(const bf16x8*)(s_kt + byte);
        s[0][kf] = __builtin_amdgcn_mfma_f32_16x16x32_bf16(qf[0][kc], kfr, s[0][kf], 0, 0, 0);
        s[1][kf] = __builtin_amdgcn_mfma_f32_16x16x32_bf16(qf[1][kc], kfr, s[1][kf], 0, 0, 0);
      }
    }

    // --- scale + rel bias + online softmax + P->LDS ---
    #pragma unroll
    for (int rb = 0; rb < 2; ++rb) {
      #pragma unroll
      for (int kf = 0; kf < 4; ++kf) {
        int kh = (kt0 >> 5) + (kf >> 1);
        int kw = ((kf & 1) << 4) + c16;
        #pragma unroll
        for (int r = 0; r < 4; ++r) {
          int lrow = w * 32 + rb * 16 + g16 * 4 + r;
          s[rb][kf][r] = s[rb][kf][r] * scale + s_relh[lrow * 32 + kh] + s_relw[lrow * 32 + kw];
        }
      }
      #pragma unroll
      for (int r = 0; r < 4; ++r) {
        float tm = fmaxf(fmaxf(s[rb][0][r], s[rb][1][r]), fmaxf(s[rb][2][r], s[rb][3][r]));
        tm = fmaxf(tm, __shfl_xor(tm, 1));
        tm = fmaxf(tm, __shfl_xor(tm, 2));
        tm = fmaxf(tm, __shfl_xor(tm, 4));
        tm = fmaxf(tm, __shfl_xor(tm, 8));
        float mnew = fmaxf(m_r[rb][r], tm);
        float fac = __expf(m_r[rb][r] - mnew);
        m_r[rb][r] = mnew;
        float psum = 0.f;
        #pragma unroll
        for (int kf = 0; kf < 4; ++kf) {
          float p = __expf(s[rb][kf][r] - mnew);
          s[rb][kf][r] = p;
          psum += p;
        }
        psum += __shfl_xor(psum, 1);
        psum += __shfl_xor(psum, 2);
        psum += __shfl_xor(psum, 4);
        psum += __shfl_xor(psum, 8);
        l_r[rb][r] = l_r[rb][r] * fac + psum;
        #pragma unroll
        for (int hf = 0; hf < 4; ++hf) o[rb][hf] *= fac;
      }
      #pragma unroll
      for (int kf = 0; kf < 4; ++kf) {
        int key = kf * 16 + c16;
        #pragma unroll
        for (int r = 0; r < 4; ++r) {
          int prow = rb * 16 + g16 * 4 + r;
          int byte = w * 4096 + prow * 128 + ((key * 2) ^ ((prow & 7) << 4));
          *(__hip_bfloat16*)(s_pt + byte) = __float2bfloat16(s[rb][kf][r]);
        }
      }
    }
    __syncthreads();

    // --- O += P V ---
    #pragma unroll
    for (int kc = 0; kc < 2; ++kc) {
      bf16x8 pf[2];
      #pragma unroll
      for (int rb = 0; rb < 2; ++rb) {
        int prow = rb * 16 + c16;
        int byte = w * 4096 + prow * 128 + (((kc * 32 + g16 * 8) * 2) ^ ((prow & 7) << 4));
        pf[rb] = *(const bf16x8*)(s_pt + byte);
      }
      #pragma unroll
      for (int hf = 0; hf < 4; ++hf) {
        int hd = hf * 16 + c16;
        int byte = hd * 128 + (((kc * 32 + g16 * 8) * 2) ^ ((hd & 7) << 4));
        bf16x8 vf = *(const bf16x8*)(s_vt + byte);
        o[0][hf] = __builtin_amdgcn_mfma_f32_16x16x32_bf16(pf[0], vf, o[0][hf], 0, 0, 0);
        o[1][hf] = __builtin_amdgcn_mfma_f32_16x16x32_bf16(pf[1], vf, o[1][hf], 0, 0, 0);
      }
    }
    __syncthreads();
  }

  // --- epilogue: normalize + write O in (B,N,C) layout ---
  const int b = bh / 12, head = bh % 12;
  #pragma unroll
  for (int rb = 0; rb < 2; ++rb) {
    #pragma unroll
    for (int r = 0; r < 4; ++r) {
      int row = q0 + w * 32 + rb * 16 + g16 * 4 + r;
      float inv = 1.0f / l_r[rb][r];
      size_t base = ((size_t)b * 1024 + row) * 768 + head * 64;
      #pragma unroll
      for (int hf = 0; hf < 4; ++hf)
        Ows[base + hf * 16 + c16] = __float2bfloat16(o[rb][hf][r] * inv);
    }
  }
}

// ---------------- launch ----------------
extern "C" void kernel_launch(void* const* d_in, const int* in_sizes, int n_in,
                              void* d_out, int out_size, void* d_ws, size_t ws_size,
                              hipStream_t stream) {
  const float* x      = (const float*)d_in[0];
  const float* qkv_w  = (const float*)d_in[1];
  const float* qkv_b  = (const float*)d_in[2];
  const float* proj_w = (const float*)d_in[3];
  const float* proj_b = (const float*)d_in[4];
  const float* rph    = (const float*)d_in[5];
  const float* rpw    = (const float*)d_in[6];

  char* ws = (char*)d_ws;
  __hip_bfloat16* xb    = (__hip_bfloat16*)(ws);              // 12582912 B (reused as Ows)
  __hip_bfloat16* wqkv  = (__hip_bfloat16*)(ws + 12582912);   // 3538944 B
  __hip_bfloat16* wproj = (__hip_bfloat16*)(ws + 16121856);   // 1179648 B
  __hip_bfloat16* Qws   = (__hip_bfloat16*)(ws + 17301504);   // 12582912 B
  __hip_bfloat16* Kws   = (__hip_bfloat16*)(ws + 29884416);   // 12582912 B
  __hip_bfloat16* Vws   = (__hip_bfloat16*)(ws + 42467328);   // 12582912 B
  __hip_bfloat16* rphb  = (__hip_bfloat16*)(ws + 55050240);   // 8192 B (64x64, row 63 = 0)
  __hip_bfloat16* rpwb  = (__hip_bfloat16*)(ws + 55058432);   // 8192 B
  __hip_bfloat16* Ows   = xb;                                  // reuse (x consumed by qkv GEMM)

  float* out   = (float*)d_out;
  float* prekv = out + 6291456;

  cvt_bf16<<<6144, 256, 0, stream>>>(x, xb, 1572864);
  cvt_bf16<<<1728, 256, 0, stream>>>(qkv_w, wqkv, 442368);
  cvt_bf16<<<576, 256, 0, stream>>>(proj_w, wproj, 147456);
  cvt_bf16_pad<<<4, 256, 0, stream>>>(rph, rphb, 1008, 1024);
  cvt_bf16_pad<<<4, 256, 0, stream>>>(rpw, rpwb, 1008, 1024);
  gemm_qkv_kernel<<<dim3(18, 64), 256, 0, stream>>>(xb, wqkv, qkv_b, Qws, Kws, Vws, prekv);
  flash_attn<<<768, 256, 0, stream>>>(Qws, Kws, Vws, rphb, rpwb, Ows);
  gemm_proj_kernel<<<dim3(6, 64), 256, 0, stream>>>(Ows, wproj, proj_b, out);
}